// Round 7
// baseline (211.366 us; speedup 1.0000x reference)
//
#include <hip/hip_runtime.h>
#include <math.h>

#define BB 1024
#define S 32
#define DIM 64
#define NREL 237
#define SIGMA 0.1f

// ---- workspace layout (float offsets) ----
#define OFS_WR    0                       // 238*64 : Wr = relf_ext @ W_agg0 (row 237 = 0)

// LDS map (floats), gather phase:
//   s_wr    [0,15232)        238 x 64, natural stride (16 float4/row)
//   s_r2m8  [15232,16256)    uchar[4096]: 4 units x 32 j x 32 s
//   s_r1u   [16256,16288)    uchar[128]: 4 units x 32
//   s_m1    [16288,16416)    float, 4 x 32
//   s_ent2  [16416,16544)    int, 4 x 32
//   s_wp    [16544,17568)    float4[4u][4wave][16c]
//   s_ov    [17568,17824)    4 x 64 (persists into epilogue)
// epilogue aliases [0,2560):
//   s_x [0,960) 4x240 | s_xt [960,1440) 2x240 | s_out [1440,1920) 2x240
//   s_red [1920,2432) 2x256 | s_h [2432,2560) 2x64
// total 17824 floats = 71296 B -> 2 blocks/CU.
#define LDS_BYTES 71296

__device__ __forceinline__ float selu_f(float x) {
    const float alpha = 1.6732632423543772f;
    const float scale = 1.0507009873554805f;
    return scale * (x > 0.f ? x : alpha * expm1f(x));
}

// ---------- Kernel A: Wr only (238 blocks, one row each, 16-deep chains) ----------
__global__ __launch_bounds__(256) void pre_wr_kernel(
    const float* __restrict__ rel_feat, const float* __restrict__ W0,
    float* __restrict__ ws) {
    __shared__ float red[256];
    const int r = blockIdx.x;              // 0..237
    const int tid = threadIdx.x;
    const int o = tid & 63, q = tid >> 6;  // 4-way k-split
    float acc = 0.f;
    if (r < NREL) {
#pragma unroll
        for (int d = q * 16; d < q * 16 + 16; ++d)
            acc += rel_feat[r * 64 + d] * W0[d * 64 + o];
    }
    red[tid] = acc;
    __syncthreads();
    if (q == 0)
        ws[OFS_WR + r * 64 + o] = red[o] + red[64 + o] + red[128 + o] + red[192 + o];
}

// ---------- Kernel GF: gather + epilogue fused, 2 b's per block ----------
__global__ __launch_bounds__(256) void gf_kernel(
    const int* __restrict__ ep, const int* __restrict__ te_arr,
    const int* __restrict__ e2e_tab, const int* __restrict__ e2ent,
    const int* __restrict__ e2r, const float* __restrict__ b0,
    const float* __restrict__ t_arr, const float* __restrict__ eps,
    const float* __restrict__ W1, const float* __restrict__ b1,
    const float* __restrict__ W_out, const float* __restrict__ b_out,
    const float* __restrict__ mW1, const float* __restrict__ mb1,
    const float* __restrict__ mW2, const float* __restrict__ mb2,
    const float* __restrict__ mW3, const float* __restrict__ mb3,
    const float* __restrict__ mW4, const float* __restrict__ mb4,
    const float* __restrict__ ws, float* __restrict__ out) {
    extern __shared__ float smem[];
    float*         s_wr   = smem;
    unsigned char* s_r2m8 = (unsigned char*)(smem + 15232);
    unsigned char* s_r1u  = (unsigned char*)(smem + 16256);
    float*         s_m1   = smem + 16288;
    int*           s_ent2 = (int*)(smem + 16416);
    float*         s_wp   = smem + 16544;
    float*         s_ov   = smem + 17568;

    const int tid = threadIdx.x;
    const int bb = blockIdx.x * 2;
    const int g = tid >> 4;                // 16 groups of 16 threads
    const int c = tid & 15;
    const int te0 = te_arr[bb];
    const int te1 = te_arr[bb + 1];
    const float4 b0v = ((const float4*)b0)[c];

    // stage Wr into LDS (natural stride; quarter-wave row reads are 2/bank)
    {
        const float4* src = (const float4*)(ws + OFS_WR);
        float4* dst = (float4*)s_wr;
        for (int i = tid; i < 238 * 16; i += 256) dst[i] = src[i];
    }
    const float4* sWr4 = (const float4*)s_wr;

    // stage-1 indices for all 4 (b,side) units
    if (tid < 128) {
        int u = tid >> 5, s = tid & 31;
        int b = bb + (u >> 1), side = u & 1;
        int te = (u >> 1) ? te1 : te0;
        int ent = ep[b * 2 + side];
        int e1 = e2e_tab[ent * S + s];
        s_r1u[u * 32 + s] = (unsigned char)e2r[e1];
        s_m1[u * 32 + s] = (e1 != te) ? 1.0f : 0.0f;
        s_ent2[u * 32 + s] = e2ent[e1];
    }
    __syncthreads();

    // stage-2: ALL 4 units' r2m as u8 — 16 independent 2-deep chains/thread
    for (int p = tid; p < 4096; p += 256) {
        int u = p >> 10, q = p & 1023, j = q >> 5, s2 = q & 31;
        int te = (u >> 1) ? te1 : te0;
        int e2 = e2e_tab[s_ent2[u * 32 + j] * S + s2];
        s_r2m8[p] = (unsigned char)((e2 == te) ? NREL : e2r[e2]);
    }
    __syncthreads();

    // barrier-free 4-unit gather; partials reduced via shfl, staged in s_wp
    const float inv = 1.0f / 32.0f;
    for (int u = 0; u < 4; ++u) {
        const int jA = g, jB = g + 16;
        float4 aA = sWr4[(int)s_r1u[u * 32 + jA] * 16 + c];
        float4 aB = sWr4[(int)s_r1u[u * 32 + jB] * 16 + c];
        const uint4* pA = (const uint4*)(s_r2m8 + u * 1024 + jA * 32);
        const uint4* pB = (const uint4*)(s_r2m8 + u * 1024 + jB * 32);
        uint4 iA0 = pA[0], iA1 = pA[1];
        uint4 iB0 = pB[0], iB1 = pB[1];
        float4 sA = make_float4(0.f, 0.f, 0.f, 0.f);
        float4 sB = make_float4(0.f, 0.f, 0.f, 0.f);
#define ACC4(sum, word) { unsigned int wv = (word);                       \
        float4 v0 = sWr4[(wv & 255u) * 16 + c];                           \
        float4 v1 = sWr4[((wv >> 8) & 255u) * 16 + c];                    \
        float4 v2 = sWr4[((wv >> 16) & 255u) * 16 + c];                   \
        float4 v3 = sWr4[(wv >> 24) * 16 + c];                            \
        sum.x += (v0.x + v1.x) + (v2.x + v3.x);                           \
        sum.y += (v0.y + v1.y) + (v2.y + v3.y);                           \
        sum.z += (v0.z + v1.z) + (v2.z + v3.z);                           \
        sum.w += (v0.w + v1.w) + (v2.w + v3.w); }
        ACC4(sA, iA0.x) ACC4(sB, iB0.x)
        ACC4(sA, iA0.y) ACC4(sB, iB0.y)
        ACC4(sA, iA0.z) ACC4(sB, iB0.z)
        ACC4(sA, iA0.w) ACC4(sB, iB0.w)
        ACC4(sA, iA1.x) ACC4(sB, iB1.x)
        ACC4(sA, iA1.y) ACC4(sB, iB1.y)
        ACC4(sA, iA1.z) ACC4(sB, iB1.z)
        ACC4(sA, iA1.w) ACC4(sB, iB1.w)
#undef ACC4
        float mA = s_m1[u * 32 + jA];
        float mB = s_m1[u * 32 + jB];
        float4 r;
        r.x = fmaxf(aA.x + sA.x * inv + b0v.x, 0.f) * mA
            + fmaxf(aB.x + sB.x * inv + b0v.x, 0.f) * mB;
        r.y = fmaxf(aA.y + sA.y * inv + b0v.y, 0.f) * mA
            + fmaxf(aB.y + sB.y * inv + b0v.y, 0.f) * mB;
        r.z = fmaxf(aA.z + sA.z * inv + b0v.z, 0.f) * mA
            + fmaxf(aB.z + sB.z * inv + b0v.z, 0.f) * mB;
        r.w = fmaxf(aA.w + sA.w * inv + b0v.w, 0.f) * mA
            + fmaxf(aB.w + sB.w * inv + b0v.w, 0.f) * mB;
        // reduce over the 4 g's within the wave (lane bits 4,5)
        r.x += __shfl_xor(r.x, 16); r.x += __shfl_xor(r.x, 32);
        r.y += __shfl_xor(r.y, 16); r.y += __shfl_xor(r.y, 32);
        r.z += __shfl_xor(r.z, 16); r.z += __shfl_xor(r.z, 32);
        r.w += __shfl_xor(r.w, 16); r.w += __shfl_xor(r.w, 32);
        if ((tid & 63) < 16)
            ((float4*)s_wp)[(u * 4 + (tid >> 6)) * 16 + c] = r;
    }
    __syncthreads();
    // cross-wave reduce: 256 threads cover 4 units x 64 components
    {
        int u = tid >> 6, w = tid & 63;
        int base = (u * 4 * 16 + (w >> 2)) * 4 + (w & 3);
        float s = s_wp[base] + s_wp[base + 64] + s_wp[base + 128] + s_wp[base + 192];
        s_ov[u * 64 + w] = s * inv;
    }
    __syncthreads();

    // ---------------- epilogue (aliases s_wr region; s_ov safe) ----------------
    float* s_x   = smem;           // 4*240 : x[u][k] = ovec_u @ W1 + b1
    float* s_xt  = smem + 960;     // 2*240
    float* s_out = smem + 1440;    // 2*240
    float* s_red = smem + 1920;    // 2*256
    float* s_h   = smem + 2432;    // 2*64
    const float tb0v = t_arr[bb];
    const float tb1v = t_arr[bb + 1];

    if (tid < NREL) {
        float y0 = 0.f, y1 = 0.f, y2 = 0.f, y3 = 0.f;
#pragma unroll 4
        for (int d = 0; d < 64; ++d) {
            float w1v = W1[d * 237 + tid];
            y0 += s_ov[d] * w1v;       y1 += s_ov[64 + d] * w1v;
            y2 += s_ov[128 + d] * w1v; y3 += s_ov[192 + d] * w1v;
        }
        float bv = b1[tid];
        s_x[tid] = y0 + bv;       s_x[240 + tid] = y1 + bv;
        s_x[480 + tid] = y2 + bv; s_x[720 + tid] = y3 + bv;
    }
    __syncthreads();

    if (tid < NREL) {
        // xt per b (linearity: b1 mixes to b1)
        s_xt[tid]       = (1.f - tb0v) * s_x[tid] + tb0v * s_x[240 + tid]
                        + SIGMA * eps[bb * 237 + tid];
        s_xt[240 + tid] = (1.f - tb1v) * s_x[480 + tid] + tb1v * s_x[720 + tid]
                        + SIGMA * eps[(bb + 1) * 237 + tid];
        // out GEMV with raw W_out (both b's share weight loads)
        float a0 = b_out[tid], a1 = a0;
#pragma unroll 2
        for (int k = 0; k < NREL; ++k) {
            float wt = W_out[k * 237 + tid];
            float wb = W_out[(237 + k) * 237 + tid];
            a0 += s_x[k] * wt + s_x[240 + k] * wb;
            a1 += s_x[480 + k] * wt + s_x[720 + k] * wb;
        }
        s_out[tid] = a0; s_out[240 + tid] = a1;
    }
    __syncthreads();

    // h1[w] = selu(mb1 + t*mW1[237] + Σ_k xt[k]·mW1[k,w])  (k-split by 4)
    {
        int w = tid & 63, gg = tid >> 6;
        float a0 = 0.f, a1 = 0.f;
        int k0 = gg * 60, k1 = (gg == 3) ? 237 : (k0 + 60);
#pragma unroll 4
        for (int k = k0; k < k1; ++k) {
            float m = mW1[k * 64 + w];
            a0 += s_xt[k] * m;
            a1 += s_xt[240 + k] * m;
        }
        s_red[tid] = a0; s_red[256 + tid] = a1;
    }
    __syncthreads();
    if (tid < 128) {
        int p = tid >> 6, w = tid & 63;
        float tb = p ? tb1v : tb0v;
        float h = mb1[w] + tb * mW1[237 * 64 + w]
                + s_red[p * 256 + w] + s_red[p * 256 + 64 + w]
                + s_red[p * 256 + 128 + w] + s_red[p * 256 + 192 + w];
        s_h[p * 64 + w] = selu_f(h);
    }
    __syncthreads();

    // h2
    {
        int w = tid & 63, gg = tid >> 6;
        float a0 = 0.f, a1 = 0.f;
#pragma unroll
        for (int d = gg * 16; d < gg * 16 + 16; ++d) {
            float m = mW2[d * 64 + w];
            a0 += s_h[d] * m; a1 += s_h[64 + d] * m;
        }
        s_red[tid] = a0; s_red[256 + tid] = a1;
    }
    __syncthreads();
    if (tid < 128) {
        int p = tid >> 6, w = tid & 63;
        float v = mb2[w] + s_red[p * 256 + w] + s_red[p * 256 + 64 + w]
                + s_red[p * 256 + 128 + w] + s_red[p * 256 + 192 + w];
        s_h[p * 64 + w] = selu_f(v);
    }
    __syncthreads();

    // h3
    {
        int w = tid & 63, gg = tid >> 6;
        float a0 = 0.f, a1 = 0.f;
#pragma unroll
        for (int d = gg * 16; d < gg * 16 + 16; ++d) {
            float m = mW3[d * 64 + w];
            a0 += s_h[d] * m; a1 += s_h[64 + d] * m;
        }
        s_red[tid] = a0; s_red[256 + tid] = a1;
    }
    __syncthreads();
    if (tid < 128) {
        int p = tid >> 6, w = tid & 63;
        float v = mb3[w] + s_red[p * 256 + w] + s_red[p * 256 + 64 + w]
                + s_red[p * 256 + 128 + w] + s_red[p * 256 + 192 + w];
        s_h[p * 64 + w] = selu_f(v);
    }
    __syncthreads();

    // vt[c] and final product
    if (tid < NREL) {
        float a0 = mb4[tid], a1 = a0;
#pragma unroll 4
        for (int w = 0; w < 64; ++w) {
            float m = mW4[w * 237 + tid];
            a0 += s_h[w] * m; a1 += s_h[64 + w] * m;
        }
        out[bb * 237 + tid] = s_out[tid] * a0;
        out[(bb + 1) * 237 + tid] = s_out[240 + tid] * a1;
    }
}

extern "C" void kernel_launch(void* const* d_in, const int* in_sizes, int n_in,
                              void* d_out, int out_size, void* d_ws, size_t ws_size,
                              hipStream_t stream) {
    const int* ep       = (const int*)d_in[0];
    const int* te       = (const int*)d_in[1];
    // d_in[2] = labels : dead code in the reference
    const int* e2e      = (const int*)d_in[3];
    const int* e2ent    = (const int*)d_in[4];
    const int* e2r      = (const int*)d_in[5];
    const float* t      = (const float*)d_in[6];
    const float* eps    = (const float*)d_in[7];
    const float* relf   = (const float*)d_in[8];
    const float* W0     = (const float*)d_in[9];
    const float* b0     = (const float*)d_in[10];
    const float* W1     = (const float*)d_in[11];
    const float* b1     = (const float*)d_in[12];
    const float* W_out  = (const float*)d_in[13];
    const float* b_out  = (const float*)d_in[14];
    const float* mW1    = (const float*)d_in[15];
    const float* mb1    = (const float*)d_in[16];
    const float* mW2    = (const float*)d_in[17];
    const float* mb2    = (const float*)d_in[18];
    const float* mW3    = (const float*)d_in[19];
    const float* mb3    = (const float*)d_in[20];
    const float* mW4    = (const float*)d_in[21];
    const float* mb4    = (const float*)d_in[22];
    float* ws  = (float*)d_ws;
    float* out = (float*)d_out;

    hipLaunchKernelGGL(pre_wr_kernel, dim3(238), dim3(256), 0, stream,
                       relf, W0, ws);
    hipLaunchKernelGGL(gf_kernel, dim3(BB / 2), dim3(256), LDS_BYTES, stream,
                       ep, te, e2e, e2ent, e2r, b0,
                       t, eps, W1, b1, W_out, b_out,
                       mW1, mb1, mW2, mb2, mW3, mb3, mW4, mb4, ws, out);
}

// Round 8
// 147.488 us; speedup vs baseline: 1.4331x; 1.4331x over previous
//
#include <hip/hip_runtime.h>
#include <math.h>

#define BB 1024
#define S 32
#define DIM 64
#define NREL 237
#define SIGMA 0.1f

// ---- workspace layout (float offsets) ----
#define OFS_WR    0                       // 238*64  : Wr = relf_ext @ W_agg0 (row 237 = 0)
#define N_WR      (238*64)
#define OFS_WC0   (OFS_WR + N_WR)         // 64*237  : W_agg1 @ W_out[:237]
#define N_WC      (64*237)
#define OFS_WC1   (OFS_WC0 + N_WC)        // 64*237  : W_agg1 @ W_out[237:]
#define OFS_BC    (OFS_WC1 + N_WC)        // 237
#define OFS_HC    (OFS_BC + 237)          // 64

// LDS map (floats), gather phase (R4 layout, natural stride 16 f4/row):
//   s_wr   [0,15232)   s_r2m [15232,16256) int   s_r1 [16256,16384) int
//   s_ent2 [16384,16512) int   s_m1 [16512,16640)   s_v1 [16640,18816) 32x68
//   s_ov   [18816,19072) 4x64 (persists into epilogue)
// epilogue aliases [0,1728). total 19072 floats = 76288 B -> 2 blocks/CU.
// 512 thr/block x 2 blocks/CU = 16 waves/CU (the R8 occupancy lever).
#define LDS_BYTES 76288

__device__ __forceinline__ float selu_f(float x) {
    const float alpha = 1.6732632423543772f;
    const float scale = 1.0507009873554805f;
    return scale * (x > 0.f ? x : alpha * expm1f(x));
}

// ---------- Kernel A: fold b-independent linear algebra (R4 verbatim) ----------
__global__ __launch_bounds__(256) void precompute_kernel(
    const float* __restrict__ rel_feat, const float* __restrict__ W0,
    const float* __restrict__ W1, const float* __restrict__ b1,
    const float* __restrict__ W_out, const float* __restrict__ b_out,
    const float* __restrict__ mW1, const float* __restrict__ mb1,
    float* __restrict__ ws) {
    __shared__ float red[256];
    int blk = blockIdx.x;
    const int tid = threadIdx.x;

    if (blk < 60) {                        // Wr[r][o], 64-deep
        int idx = blk * 256 + tid;
        if (idx < 238 * 64) {
            int r = idx >> 6, o = idx & 63;
            float acc = 0.f;
            if (r < NREL) {
#pragma unroll 8
                for (int d = 0; d < 64; ++d)
                    acc += rel_feat[r * 64 + d] * W0[d * 64 + o];
            }
            ws[OFS_WR + idx] = acc;        // row 237 stays 0
        }
        return;
    }
    blk -= 60;
    if (blk < 512) {                       // Wc0 / Wc1 : 64x237 each, 237-deep
        int half = blk >> 8;
        int lb = blk & 255;
        int o = lb >> 2, ct = lb & 3;
        int cl = tid & 63, g = tid >> 6;
        int c = ct * 64 + cl;
        const float* Wsrc = W_out + half * 237 * 237;
        float acc = 0.f;
        if (c < NREL) {
            int k0 = g * 60, k1 = (g == 3) ? 237 : (k0 + 60);
#pragma unroll 4
            for (int k = k0; k < k1; ++k)
                acc += W1[o * 237 + k] * Wsrc[k * 237 + c];
        }
        red[tid] = acc;
        __syncthreads();
        if (g == 0 && c < NREL) {
            float s = red[cl] + red[64 + cl] + red[128 + cl] + red[192 + cl];
            ws[(half ? OFS_WC1 : OFS_WC0) + o * 237 + c] = s;
        }
        return;
    }
    blk -= 512;
    if (blk < 4) {                         // bc[c]
        int cl = tid & 63, g = tid >> 6;
        int c = blk * 64 + cl;
        float acc = 0.f;
        if (c < NREL) {
            int k0 = g * 60, k1 = (g == 3) ? 237 : (k0 + 60);
#pragma unroll 4
            for (int k = k0; k < k1; ++k)
                acc += b1[k] * (W_out[k * 237 + c] + W_out[(237 + k) * 237 + c]);
        }
        red[tid] = acc;
        __syncthreads();
        if (g == 0 && c < NREL)
            ws[OFS_BC + c] = b_out[c] + red[cl] + red[64 + cl] + red[128 + cl] + red[192 + cl];
        return;
    }
    // hc[w]
    {
        int w = tid & 63, g = tid >> 6;
        int k0 = g * 60, k1 = (g == 3) ? 237 : (k0 + 60);
        float acc = 0.f;
#pragma unroll 4
        for (int k = k0; k < k1; ++k)
            acc += b1[k] * mW1[k * 64 + w];
        red[tid] = acc;
        __syncthreads();
        if (g == 0)
            ws[OFS_HC + w] = mb1[w] + red[w] + red[64 + w] + red[128 + w] + red[192 + w];
    }
}

// ---------- Kernel GF: gather + epilogue fused, 2 b's per block, 512 threads ----------
__global__ __launch_bounds__(512) void gf_kernel(
    const int* __restrict__ ep, const int* __restrict__ te_arr,
    const int* __restrict__ e2e_tab, const int* __restrict__ e2ent,
    const int* __restrict__ e2r, const float* __restrict__ b0,
    const float* __restrict__ t_arr, const float* __restrict__ eps,
    const float* __restrict__ W1, const float* __restrict__ mW1,
    const float* __restrict__ mW2, const float* __restrict__ mb2,
    const float* __restrict__ mW3, const float* __restrict__ mb3,
    const float* __restrict__ mW4, const float* __restrict__ mb4,
    const float* __restrict__ ws, float* __restrict__ out) {
    extern __shared__ float smem[];
    float* s_wr   = smem;
    int*   s_r2m  = (int*)(smem + 15232);
    int*   s_r1   = (int*)(smem + 16256);
    int*   s_ent2 = (int*)(smem + 16384);
    float* s_m1   = smem + 16512;
    float* s_v1   = smem + 16640;
    float* s_ov   = smem + 18816;

    const int tid = threadIdx.x;
    const int bb = blockIdx.x * 2;
    const int g = tid >> 4;                // 32 groups of 16 threads: one j each
    const int c = tid & 15;
    const int te0 = te_arr[bb];
    const int te1 = te_arr[bb + 1];
    const float4 b0v = ((const float4*)b0)[c];

    // stage Wr into LDS (natural stride 16 float4s; quarter-wave row = 2/bank)
    {
        const float4* src = (const float4*)(ws + OFS_WR);
        float4* dst = (float4*)s_wr;
        for (int i = tid; i < 238 * 16; i += 512) dst[i] = src[i];
    }
    const float4* sWr4 = (const float4*)s_wr;

    // hoisted stage-1 for all 4 (b,side) units
    if (tid < 128) {
        int u = tid >> 5, s = tid & 31;
        int b = bb + (u >> 1), side = u & 1;
        int te = (u >> 1) ? te1 : te0;
        int ent = ep[b * 2 + side];
        int e1 = e2e_tab[ent * S + s];
        s_r1[u * 32 + s] = e2r[e1];
        s_m1[u * 32 + s] = (e1 != te) ? 1.0f : 0.0f;
        s_ent2[u * 32 + s] = e2ent[e1];
    }
    __syncthreads();

    // prologue: build r2m for unit 0
    for (int p = tid; p < 1024; p += 512) {
        int j = p >> 5, s = p & 31;
        int e2 = e2e_tab[s_ent2[j] * S + s];
        s_r2m[p] = (e2 == te0) ? NREL : e2r[e2];
    }
    __syncthreads();

    const float inv = 1.0f / 32.0f;
    for (int u = 0; u < 4; ++u) {
        // this thread owns j = g: one 33-read accumulate stream
        {
            const int j = g;
            const int* rr = &s_r2m[j * 32];
            float4 acc = sWr4[s_r1[u * 32 + j] * 16 + c];
            float4 sa = make_float4(0.f, 0.f, 0.f, 0.f);
            float4 sb = make_float4(0.f, 0.f, 0.f, 0.f);
#pragma unroll
            for (int s = 0; s < 16; ++s) {
                float4 v = sWr4[rr[s] * 16 + c];
                sa.x += v.x; sa.y += v.y; sa.z += v.z; sa.w += v.w;
            }
#pragma unroll
            for (int s = 16; s < 32; ++s) {
                float4 v = sWr4[rr[s] * 16 + c];
                sb.x += v.x; sb.y += v.y; sb.z += v.z; sb.w += v.w;
            }
            float m = s_m1[u * 32 + j];
            float4 r;
            r.x = fmaxf(acc.x + (sa.x + sb.x) * inv + b0v.x, 0.f) * m;
            r.y = fmaxf(acc.y + (sa.y + sb.y) * inv + b0v.y, 0.f) * m;
            r.z = fmaxf(acc.z + (sa.z + sb.z) * inv + b0v.z, 0.f) * m;
            r.w = fmaxf(acc.w + (sa.w + sb.w) * inv + b0v.w, 0.f) * m;
            *((float4*)&s_v1[j * 68 + c * 4]) = r;
        }
        __syncthreads();
        // reduce (first 64 threads) + build r2m for u+1 (all threads)
        if (tid < 64) {
            float sum = 0.f;
#pragma unroll 8
            for (int j = 0; j < 32; ++j) sum += s_v1[j * 68 + tid];
            s_ov[u * 64 + tid] = sum * inv;
        }
        if (u < 3) {
            const int un = u + 1;
            const int te = (un >> 1) ? te1 : te0;
            for (int p = tid; p < 1024; p += 512) {
                int j = p >> 5, s = p & 31;
                int e2 = e2e_tab[s_ent2[un * 32 + j] * S + s];
                s_r2m[p] = (e2 == te) ? NREL : e2r[e2];
            }
        }
        __syncthreads();
    }

    // ---------------- epilogue: each 256-thread half owns one b ----------------
    float* s_omix = smem;          // 2*64
    float* s_ymix = smem + 128;    // 2*240
    float* s_outv = smem + 608;    // 2*240
    float* s_red  = smem + 1088;   // 2*256
    float* s_h    = smem + 1600;   // 2*64
    const float* Wc0 = ws + OFS_WC0;
    const float* Wc1 = ws + OFS_WC1;
    const float* bc = ws + OFS_BC;
    const float* hc = ws + OFS_HC;

    const int p  = tid >> 8;       // half id: this half handles b = bb + p
    const int lt = tid & 255;
    const float tb = t_arr[bb + p];

    if (lt < 64) {
        float o0 = s_ov[(p * 2 + 0) * 64 + lt];
        float o1 = s_ov[(p * 2 + 1) * 64 + lt];
        s_omix[p * 64 + lt] = (1.f - tb) * o0 + tb * o1;
    }
    __syncthreads();

    if (lt < NREL) {
        // ymix[k] = omix @ W1[:,k];  out[c] = bc + ov0@Wc0 + ov1@Wc1
        float y = 0.f, a = bc[lt];
#pragma unroll 4
        for (int d = 0; d < 64; ++d) {
            y += s_omix[p * 64 + d] * W1[d * 237 + lt];
            a += s_ov[p * 128 + d] * Wc0[d * 237 + lt]
               + s_ov[p * 128 + 64 + d] * Wc1[d * 237 + lt];
        }
        s_ymix[p * 240 + lt] = y;
        s_outv[p * 240 + lt] = a;
    }
    __syncthreads();

    // h1[w] = selu(hc + t*mW1[237] + Σ_k (σ·eps[k]+ymix[k])·mW1[k,w]), k-split 4
    {
        int w = lt & 63, gg = lt >> 6;
        float a = 0.f;
        int k0 = gg * 60, k1 = (gg == 3) ? 237 : (k0 + 60);
        const float* e = eps + (bb + p) * 237;
#pragma unroll 4
        for (int k = k0; k < k1; ++k)
            a += (SIGMA * e[k] + s_ymix[p * 240 + k]) * mW1[k * 64 + w];
        s_red[p * 256 + lt] = a;
    }
    __syncthreads();
    if (lt < 64) {
        float h = hc[lt] + tb * mW1[237 * 64 + lt]
                + s_red[p * 256 + lt] + s_red[p * 256 + 64 + lt]
                + s_red[p * 256 + 128 + lt] + s_red[p * 256 + 192 + lt];
        s_h[p * 64 + lt] = selu_f(h);
    }
    __syncthreads();

    // h2
    {
        int w = lt & 63, gg = lt >> 6;
        float a = 0.f;
#pragma unroll
        for (int d = gg * 16; d < gg * 16 + 16; ++d)
            a += s_h[p * 64 + d] * mW2[d * 64 + w];
        s_red[p * 256 + lt] = a;
    }
    __syncthreads();
    if (lt < 64) {
        float v = mb2[lt] + s_red[p * 256 + lt] + s_red[p * 256 + 64 + lt]
                + s_red[p * 256 + 128 + lt] + s_red[p * 256 + 192 + lt];
        s_h[p * 64 + lt] = selu_f(v);
    }
    __syncthreads();

    // h3
    {
        int w = lt & 63, gg = lt >> 6;
        float a = 0.f;
#pragma unroll
        for (int d = gg * 16; d < gg * 16 + 16; ++d)
            a += s_h[p * 64 + d] * mW3[d * 64 + w];
        s_red[p * 256 + lt] = a;
    }
    __syncthreads();
    if (lt < 64) {
        float v = mb3[lt] + s_red[p * 256 + lt] + s_red[p * 256 + 64 + lt]
                + s_red[p * 256 + 128 + lt] + s_red[p * 256 + 192 + lt];
        s_h[p * 64 + lt] = selu_f(v);
    }
    __syncthreads();

    // vt[c] and final product
    if (lt < NREL) {
        float a = mb4[lt];
#pragma unroll 4
        for (int w = 0; w < 64; ++w)
            a += s_h[p * 64 + w] * mW4[w * 237 + lt];
        out[(bb + p) * 237 + lt] = s_outv[p * 240 + lt] * a;
    }
}

extern "C" void kernel_launch(void* const* d_in, const int* in_sizes, int n_in,
                              void* d_out, int out_size, void* d_ws, size_t ws_size,
                              hipStream_t stream) {
    const int* ep       = (const int*)d_in[0];
    const int* te       = (const int*)d_in[1];
    // d_in[2] = labels : dead code in the reference
    const int* e2e      = (const int*)d_in[3];
    const int* e2ent    = (const int*)d_in[4];
    const int* e2r      = (const int*)d_in[5];
    const float* t      = (const float*)d_in[6];
    const float* eps    = (const float*)d_in[7];
    const float* relf   = (const float*)d_in[8];
    const float* W0     = (const float*)d_in[9];
    const float* b0     = (const float*)d_in[10];
    const float* W1     = (const float*)d_in[11];
    const float* b1     = (const float*)d_in[12];
    const float* W_out  = (const float*)d_in[13];
    const float* b_out  = (const float*)d_in[14];
    const float* mW1    = (const float*)d_in[15];
    const float* mb1    = (const float*)d_in[16];
    const float* mW2    = (const float*)d_in[17];
    const float* mb2    = (const float*)d_in[18];
    const float* mW3    = (const float*)d_in[19];
    const float* mb3    = (const float*)d_in[20];
    const float* mW4    = (const float*)d_in[21];
    const float* mb4    = (const float*)d_in[22];
    float* ws  = (float*)d_ws;
    float* out = (float*)d_out;

    hipLaunchKernelGGL(precompute_kernel, dim3(577), dim3(256), 0, stream,
                       relf, W0, W1, b1, W_out, b_out, mW1, mb1, ws);
    hipLaunchKernelGGL(gf_kernel, dim3(BB / 2), dim3(512), LDS_BYTES, stream,
                       ep, te, e2e, e2ent, e2r, b0,
                       t, eps, W1, mW1, mW2, mb2, mW3, mb3, mW4, mb4, ws, out);
}